// Round 8
// baseline (118.972 us; speedup 1.0000x reference)
//
#include <hip/hip_runtime.h>

typedef unsigned short u16;
typedef unsigned int   u32;
typedef __attribute__((ext_vector_type(8))) short short8;
typedef __attribute__((ext_vector_type(4))) float f32x4;

__device__ __forceinline__ u16 f2bf(float f) {
    u32 u = __float_as_uint(f);
    u = (u + 0x7fffu + ((u >> 16) & 1u)) >> 16;
    return (u16)u;
}

__device__ __forceinline__ void gld_lds16(const void* g, void* l) {
    __builtin_amdgcn_global_load_lds(
        (const __attribute__((address_space(1))) u32*)g,
        (__attribute__((address_space(3))) u32*)l, 16, 0, 0);
}

// ---------------------------------------------------------------------------
// prep: 5120 blocks.
//   [0,3072)      cast adj|wct fp32 -> bf16 into Ab|W0b|W1b (linear)
//   [3072,3328)   transpose+cast wct[0] -> W0T
//   [3328,3584)   transpose+cast wct[1] -> W1T
//   [3584,5120)   transpose+cast x (3072x2048) -> Xt (2048x3072)
// ---------------------------------------------------------------------------
__global__ __launch_bounds__(256) void prep_kernel(
    const float* __restrict__ x, const float* __restrict__ adj,
    const float* __restrict__ wct,
    u16* __restrict__ Ab, u16* __restrict__ W0T, u16* __restrict__ W1T,
    u16* __restrict__ Xt)
{
    __shared__ float tile[64][65];
    const int t = threadIdx.x;
    const int bid = blockIdx.x;

    if (bid < 3072) {
        const int i4 = bid * 256 + t;
        const float4 v = (i4 < 262144) ? ((const float4*)adj)[i4]
                                       : ((const float4*)wct)[i4 - 262144];
        ushort4 o;
        o.x = f2bf(v.x); o.y = f2bf(v.y); o.z = f2bf(v.z); o.w = f2bf(v.w);
        ((ushort4*)Ab)[i4] = o;
        return;
    }

    const float* src; u16* dst; int C, R, r0, c0;
    if (bid < 3328)      { const int q = bid - 3072; src = wct;           dst = W0T; C = 1024; R = 1024; r0 = (q & 15) << 6; c0 = (q >> 4) << 6; }
    else if (bid < 3584) { const int q = bid - 3328; src = wct + 1048576; dst = W1T; C = 1024; R = 1024; r0 = (q & 15) << 6; c0 = (q >> 4) << 6; }
    else                 { const int q = bid - 3584; src = x;             dst = Xt;  C = 2048; R = 3072; r0 = (q % 48) << 6; c0 = (q / 48) << 6; }

#pragma unroll
    for (int it = 0; it < 4; ++it) {
        const int f4 = it * 256 + t;
        const int r  = f4 >> 4;
        const int c4 = (f4 & 15) << 2;
        const float4 v = *(const float4*)&src[(size_t)(r0 + r) * C + c0 + c4];
        tile[r][c4]     = v.x; tile[r][c4 + 1] = v.y;
        tile[r][c4 + 2] = v.z; tile[r][c4 + 3] = v.w;
    }
    __syncthreads();
#pragma unroll
    for (int it = 0; it < 4; ++it) {
        const int f4 = it * 256 + t;
        const int u  = f4 >> 4;
        const int v4 = (f4 & 15) << 2;
        ushort4 o;
        o.x = f2bf(tile[v4][u]);     o.y = f2bf(tile[v4 + 1][u]);
        o.z = f2bf(tile[v4 + 2][u]); o.w = f2bf(tile[v4 + 3][u]);
        *(ushort4*)&dst[(size_t)(c0 + u) * R + r0 + v4] = o;
    }
}

// ---------------------------------------------------------------------------
// gemm (term-split): 1792 IDENTICAL blocks = 7/CU, each K=1024 exactly.
// Tile 64M x 128N, BK=64, 16 steps, 4 waves 2Mx2N (wave 32x64, acc 2x4).
// Single-buffer LDS (24.5 KB -> 6+ blocks/CU), m97-style 2-barrier loop:
// TLP from ~24 waves/CU hides the stage drain. Slot-XOR swizzle (R5, proven
// 0-conflict). Partial sums -> atomicAdd f32 into H32 (memset'd).
// ---------------------------------------------------------------------------
__global__ __launch_bounds__(256, 6) void gemm_h_kernel(
    const u16* __restrict__ Ab,  const u16* __restrict__ W0b,
    const u16* __restrict__ W1b, const u16* __restrict__ W0T,
    const u16* __restrict__ W1T, const u16* __restrict__ Xt,
    float* __restrict__ H32)
{
    __shared__ u16 Asm[64 * 64];    // 8 KB  [row][8 slots of 16B], swizzled
    __shared__ u16 Bsm[128 * 64];   // 16 KB

    const int tid = threadIdx.x;
    const int bid = blockIdx.x;

    // XCD-local decomposition: 224 blocks per XCD = 2 nt x 112 (mt,term)
    const int xcd  = bid & 7;
    const int idx  = bid >> 3;             // 0..223
    const int nt_l = idx / 112;
    const int j    = idx - nt_l * 112;     // 0..111
    int mt, term;
    if (j < 32)      { mt = j >> 1;               term = j & 1; }
    else if (j < 80) { const int jj = j - 32; const int q = jj / 3; mt = 16 + q; term = jj - 3 * q; }
    else             { const int jj = j - 80; mt = 32 + (jj >> 1);  term = jj & 1; }

    const int i    = mt >> 4;
    const int row0 = (mt & 15) << 6;       // rows within the 1024-block
    const int nt   = (xcd << 1) + nt_l;    // 0..15
    const int col0 = nt << 7;

    const u16* Amat; int xoff;
    if (i == 0)      { if (term == 0) { Amat = Ab;  xoff = 0;    } else { Amat = W0b; xoff = 1024; } }
    else if (i == 1) { if (term == 0) { Amat = W0T; xoff = 0;    } else if (term == 1) { Amat = Ab; xoff = 1024; } else { Amat = W1b; xoff = 2048; } }
    else             { if (term == 0) { Amat = W1T; xoff = 1024; } else { Amat = Ab;  xoff = 2048; } }
    const u16* ga = Amat + (size_t)row0 * 1024;
    const u16* gb = Xt + (size_t)col0 * 3072 + xoff;

    const int l    = tid & 63;
    const int w    = tid >> 6;
    const int wr   = ((w >> 1) & 1) << 5;   // wave M offset 0/32
    const int wc   = (w & 1) << 6;          // wave N offset 0/64
    const int lrow = l & 15;
    const int g16  = l >> 4;
    const int rsw  = lrow & 7;

    // staging: row = tid>>3 (0..31), 16B slot = tid&7, src k pre-swizzled
    const int sub  = tid >> 3;
    const int srck = ((tid & 7) ^ (sub & 7)) << 3;
    u16* AsmW = Asm + (w << 9);             // wave-uniform LDS base
    u16* BsmW = Bsm + (w << 9);

    f32x4 acc[2][4] = {};

    for (int k0 = 0; k0 < 1024; k0 += 64) {
        __syncthreads();                    // prev step's reads done
        const u16* pa = ga + (size_t)sub * 1024 + k0 + srck;
        gld_lds16(pa,             AsmW);
        gld_lds16(pa + 32 * 1024, AsmW + 2048);
        const u16* pb = gb + (size_t)sub * 3072 + k0 + srck;
        gld_lds16(pb,             BsmW);
        gld_lds16(pb + 32 * 3072, BsmW + 2048);
        gld_lds16(pb + 64 * 3072, BsmW + 4096);
        gld_lds16(pb + 96 * 3072, BsmW + 6144);
        asm volatile("s_waitcnt vmcnt(0)" ::: "memory");
        __syncthreads();                    // tile globally ready

        short8 af[2][2], bfr[2][4];
#pragma unroll
        for (int kk = 0; kk < 2; ++kk) {
            const int so = (((kk << 2) | g16) ^ rsw) << 3;
#pragma unroll
            for (int fm = 0; fm < 2; ++fm)
                af[kk][fm] = *(const short8*)&Asm[(wr + fm * 16 + lrow) * 64 + so];
#pragma unroll
            for (int fn = 0; fn < 4; ++fn)
                bfr[kk][fn] = *(const short8*)&Bsm[(wc + fn * 16 + lrow) * 64 + so];
        }
#pragma unroll
        for (int kk = 0; kk < 2; ++kk)
#pragma unroll
            for (int fm = 0; fm < 2; ++fm)
#pragma unroll
                for (int fn = 0; fn < 4; ++fn)
                    acc[fm][fn] = __builtin_amdgcn_mfma_f32_16x16x32_bf16(
                        af[kk][fm], bfr[kk][fn], acc[fm][fn], 0, 0, 0);
    }

    // epilogue: atomic-accumulate the term partial into H32
    const int rbase = g16 << 2;
#pragma unroll
    for (int fm = 0; fm < 2; ++fm)
#pragma unroll
        for (int fn = 0; fn < 4; ++fn)
#pragma unroll
            for (int r = 0; r < 4; ++r) {
                const int grow = (i << 10) + row0 + wr + fm * 16 + rbase + r;
                const int gcol = col0 + wc + fn * 16 + lrow;
                atomicAdd(&H32[(size_t)grow * 2048 + gcol], acc[fm][fn][r]);
            }
}

// ---------------------------------------------------------------------------
// glu: out(n,b,c) = GLU(h@W + bias). One block per n (3072 blocks), f32 H.
// ---------------------------------------------------------------------------
__global__ __launch_bounds__(256) void glu_kernel(
    const float* __restrict__ H, const float* __restrict__ W,
    const float* __restrict__ bias, float* __restrict__ out)
{
    __shared__ float Wsm[8192];
    __shared__ float Hsm[2048];
    const int t = threadIdx.x;
    const int n = blockIdx.x;
#pragma unroll
    for (int it = 0; it < 8; ++it) {
        const int i4 = it * 256 + t;
        *(float4*)&Wsm[i4 * 4] = *(const float4*)&W[i4 * 4];
    }
    *(float4*)&Hsm[t * 8]     = *(const float4*)&H[(size_t)n * 2048 + t * 8];
    *(float4*)&Hsm[t * 8 + 4] = *(const float4*)&H[(size_t)n * 2048 + t * 8 + 4];
    __syncthreads();

    const int c  = t & 63;
    const int bq = t >> 6;
    const float bl = bias[c], br = bias[c + 64];
    float accL[8], accR[8];
#pragma unroll
    for (int jj = 0; jj < 8; ++jj) { accL[jj] = bl; accR[jj] = br; }

    for (int k0 = 0; k0 < 64; k0 += 8) {
        float wl[8], wrg[8];
#pragma unroll
        for (int k = 0; k < 8; ++k) {
            wl[k]  = Wsm[(k0 + k) * 128 + c];
            wrg[k] = Wsm[(k0 + k) * 128 + c + 64];
        }
#pragma unroll
        for (int jj = 0; jj < 8; ++jj) {
            const float* hp = &Hsm[(bq * 8 + jj) * 64 + k0];
#pragma unroll
            for (int k = 0; k < 8; ++k) {
                accL[jj] = fmaf(hp[k], wl[k],  accL[jj]);
                accR[jj] = fmaf(hp[k], wrg[k], accR[jj]);
            }
        }
    }
#pragma unroll
    for (int jj = 0; jj < 8; ++jj) {
        const float sg = 1.0f / (1.0f + __expf(-accR[jj]));
        out[(size_t)n * 2048 + (bq * 8 + jj) * 64 + c] = accL[jj] * sg;
    }
}

// ---------------------------------------------------------------------------
extern "C" void kernel_launch(void* const* d_in, const int* in_sizes, int n_in,
                              void* d_out, int out_size, void* d_ws, size_t ws_size,
                              hipStream_t stream)
{
    const float* x    = (const float*)d_in[0];   // (3072, 32, 64)
    const float* adj  = (const float*)d_in[1];   // (1024, 1024)
    const float* wct  = (const float*)d_in[2];   // (2, 1024, 1024)
    const float* W    = (const float*)d_in[3];   // (64, 128)
    const float* bias = (const float*)d_in[4];   // (128,)
    float* out = (float*)d_out;

    char* ws = (char*)d_ws;
    u16*   Xt  = (u16*)ws;                    // bf16 [2048][3072]
    u16*   Ab  = (u16*)(ws + 12582912);       // 3 x 1M bf16 (Ab|W0b|W1b)
    u16*   W0b = Ab + 1048576;
    u16*   W1b = Ab + 2097152;
    u16*   W0T = (u16*)(ws + 18874368);       // 2 x 1M bf16
    u16*   W1T = W0T + 1048576;
    float* H32 = (float*)(ws + 23068672);     // f32 [3072][2048] (25.2 MB)

    prep_kernel<<<5120, 256, 0, stream>>>(x, adj, wct, Ab, W0T, W1T, Xt);
    hipMemsetAsync(H32, 0, (size_t)3072 * 2048 * 4, stream);
    gemm_h_kernel<<<1792, 256, 0, stream>>>(Ab, W0b, W1b, W0T, W1T, Xt, H32);
    glu_kernel<<<3072, 256, 0, stream>>>(H32, W, bias, out);
}

// Round 9
// 70.920 us; speedup vs baseline: 1.6775x; 1.6775x over previous
//
#include <hip/hip_runtime.h>

typedef unsigned short u16;
typedef unsigned int   u32;
typedef __attribute__((ext_vector_type(8))) short short8;
typedef __attribute__((ext_vector_type(16))) float f32x16;

__device__ __forceinline__ u16 f2bf(float f) {
    u32 u = __float_as_uint(f);
    u = (u + 0x7fffu + ((u >> 16) & 1u)) >> 16;
    return (u16)u;
}

__device__ __forceinline__ void gld_lds16(const void* g, void* l) {
    __builtin_amdgcn_global_load_lds(
        (const __attribute__((address_space(1))) u32*)g,
        (__attribute__((address_space(3))) u32*)l, 16, 0, 0);
}

// ---------------------------------------------------------------------------
// prep: 5122 blocks (cast + all transposes), as R5.
// ---------------------------------------------------------------------------
__global__ __launch_bounds__(256) void prep_kernel(
    const float* __restrict__ x, const float* __restrict__ adj,
    const float* __restrict__ wct, const float* __restrict__ W,
    u16* __restrict__ Ab, u16* __restrict__ W0T, u16* __restrict__ W1T,
    u16* __restrict__ Xt, u16* __restrict__ Wt)
{
    __shared__ float tile[64][65];
    const int t = threadIdx.x;
    const int bid = blockIdx.x;

    if (bid < 3072) {
        const int i4 = bid * 256 + t;
        const float4 v = (i4 < 262144) ? ((const float4*)adj)[i4]
                                       : ((const float4*)wct)[i4 - 262144];
        ushort4 o;
        o.x = f2bf(v.x); o.y = f2bf(v.y); o.z = f2bf(v.z); o.w = f2bf(v.w);
        ((ushort4*)Ab)[i4] = o;
        return;
    }

    const float* src; u16* dst; int C, R, r0, c0;
    if (bid < 3328)      { const int q = bid - 3072; src = wct;           dst = W0T; C = 1024; R = 1024; r0 = (q & 15) << 6; c0 = (q >> 4) << 6; }
    else if (bid < 3584) { const int q = bid - 3328; src = wct + 1048576; dst = W1T; C = 1024; R = 1024; r0 = (q & 15) << 6; c0 = (q >> 4) << 6; }
    else if (bid < 5120) { const int q = bid - 3584; src = x;             dst = Xt;  C = 2048; R = 3072; r0 = (q % 48) << 6; c0 = (q / 48) << 6; }
    else                 { const int q = bid - 5120; src = W;             dst = Wt;  C = 128;  R = 64;   r0 = 0;             c0 = q << 6; }

#pragma unroll
    for (int it = 0; it < 4; ++it) {
        const int f4 = it * 256 + t;
        const int r  = f4 >> 4;
        const int c4 = (f4 & 15) << 2;
        const float4 v = *(const float4*)&src[(size_t)(r0 + r) * C + c0 + c4];
        tile[r][c4]     = v.x; tile[r][c4 + 1] = v.y;
        tile[r][c4 + 2] = v.z; tile[r][c4 + 3] = v.w;
    }
    __syncthreads();
#pragma unroll
    for (int it = 0; it < 4; ++it) {
        const int f4 = it * 256 + t;
        const int u  = f4 >> 4;
        const int v4 = (f4 & 15) << 2;
        ushort4 o;
        o.x = f2bf(tile[v4][u]);     o.y = f2bf(tile[v4 + 1][u]);
        o.z = f2bf(tile[v4 + 2][u]); o.w = f2bf(tile[v4 + 3][u]);
        *(ushort4*)&dst[(size_t)(c0 + u) * R + r0 + v4] = o;
    }
}

// ---------------------------------------------------------------------------
// gemm+glu fused, 32x32x16 MFMA. Tile 128Mx128N, BK=64, 4 waves (2x2) of
// 64x64 each. A+B LDS double-buffered (64 KB -> 2 blocks/CU). Counted
// vmcnt(8). Grid 384, long (i=1, K=3072) blocks dispatched first.
// Epilogue: H-tile (128x128) -> LDS bf16 -> GLU(H@W+b) via 32x32 MFMA.
// ---------------------------------------------------------------------------
__global__ __launch_bounds__(256, 2) void gemm_h_kernel(
    const u16* __restrict__ Ab,  const u16* __restrict__ W0b,
    const u16* __restrict__ W1b, const u16* __restrict__ W0T,
    const u16* __restrict__ W1T, const u16* __restrict__ Xt,
    const u16* __restrict__ Wt,  const float* __restrict__ bias,
    float* __restrict__ out)
{
    __shared__ u16 Adb[16384];    // 2 x 16 KB; epilogue: Wsm (first 16 KB)
    __shared__ u16 Bdb[16384];    // 2 x 16 KB; epilogue: Hsm (32 KB)

    const int tid = threadIdx.x;
    const int bid = blockIdx.x;
    // seg 0 (bids 0..127) = i=1 (long); seg 1 = i=0; seg 2 = i=2.
    const int xcd = bid & 7;
    const int idx = bid >> 3;              // 0..47
    const int seg = idx >> 4;              // 0..2
    const int i   = (seg == 0) ? 1 : ((seg == 1) ? 0 : 2);
    const int sub16 = idx & 15;
    const int mt_l  = sub16 >> 1;          // 0..7
    const int nt    = (xcd << 1) + (sub16 & 1);  // 0..15
    const int row0  = mt_l << 7;
    const int col0  = nt << 7;

    const int l    = tid & 63;
    const int w    = tid >> 6;
    const int wr   = ((w >> 1) & 1) << 6;  // wave M offset 0/64
    const int wc   = (w & 1) << 6;         // wave N offset 0/64
    const int l31  = l & 31;
    const int lh   = l >> 5;
    const int l7   = l31 & 7;

    // staging: flat = p*256+tid; row = flat>>3 (0..127), 16B slot = flat&7;
    // source k pre-swizzled by slot^(row&7) (both-sides swizzle, rule #21)
    const int srow = tid >> 3;
    const int sswz = ((tid & 7) ^ (srow & 7)) << 3;
    auto stage = [&](u16* Abuf, u16* Bbuf, const u16* ta, const u16* tb, int k0) {
#pragma unroll
        for (int p = 0; p < 4; ++p) {
            const int row = (p << 5) + srow;   // p*32 + 0..31
            gld_lds16(ta + (size_t)row * 1024 + k0 + sswz,
                      Abuf + (p << 12) + ((tid >> 6) << 9) + 0);
            gld_lds16(tb + (size_t)row * 3072 + k0 + sswz,
                      Bbuf + (p << 12) + ((tid >> 6) << 9) + 0);
        }
    };
    // dest layout check: flat16B = p*256 + tid -> elem off = p*4096? No:
    // per p, rows p*32..p*32+31 (256 threads / 8 slots = 32 rows) ->
    // elems = row*64 + slot*8 = (p*32+srow)*64 + (tid&7)*8 = p*2048 + tid*8.
    // Passed base must be wave-uniform: p*2048 + (tid&~63)*8 = (p<<12 is WRONG)
    // -> use (p << 11) + ((tid >> 6) << 9). Fixed below by recomputing in-call.

    auto stage2 = [&](u16* Abuf, u16* Bbuf, const u16* ta, const u16* tb, int k0) {
#pragma unroll
        for (int p = 0; p < 4; ++p) {
            const int row = (p << 5) + srow;
            u16* db = Abuf + (p << 11) + ((tid & 192) << 3);  // p*2048 + wavebase*8
            u16* eb = Bbuf + (p << 11) + ((tid & 192) << 3);
            gld_lds16(ta + (size_t)row * 1024 + k0 + sswz, db);
            gld_lds16(tb + (size_t)row * 3072 + k0 + sswz, eb);
        }
    };

    f32x16 acc00 = {}, acc01 = {}, acc10 = {}, acc11 = {};

    const size_t rofs = (size_t)row0 * 1024;
    const size_t xb   = (size_t)col0 * 3072;
    const u16 *ca, *cb, *na, *nb, *fa = nullptr, *fb = nullptr;
    int nterms;
    if (i == 0) {
        ca = Ab  + rofs; cb = Xt + xb;
        na = W0b + rofs; nb = Xt + xb + 1024;
        nterms = 2;
    } else if (i == 1) {
        ca = W0T + rofs; cb = Xt + xb;
        na = Ab  + rofs; nb = Xt + xb + 1024;
        fa = W1b + rofs; fb = Xt + xb + 2048;
        nterms = 3;
    } else {
        ca = W1T + rofs; cb = Xt + xb + 1024;
        na = Ab  + rofs; nb = Xt + xb + 2048;
        nterms = 2;
    }

    u16 *Ac = Adb, *Ap = Adb + 8192, *Bc = Bdb, *Bp = Bdb + 8192;

    auto step = [&](const u16* pfa, const u16* pfb, int pk0, bool pf) {
        __builtin_amdgcn_s_barrier();                 // done reading Ap/Bp
        if (pf) {
            stage2(Ap, Bp, pfa, pfb, pk0);
            asm volatile("s_waitcnt vmcnt(8)" ::: "memory");
        } else {
            asm volatile("s_waitcnt vmcnt(0)" ::: "memory");
        }
        __builtin_amdgcn_s_barrier();                 // Ac/Bc globally ready

        __builtin_amdgcn_s_setprio(1);
#pragma unroll
        for (int ks = 0; ks < 4; ++ks) {
            const int off = (((ks << 1) | lh) ^ l7) << 3;
            const short8 a0 = *(const short8*)&Ac[((wr + l31) << 6) + off];
            const short8 a1 = *(const short8*)&Ac[((wr + 32 + l31) << 6) + off];
            const short8 b0 = *(const short8*)&Bc[((wc + l31) << 6) + off];
            const short8 b1 = *(const short8*)&Bc[((wc + 32 + l31) << 6) + off];
            acc00 = __builtin_amdgcn_mfma_f32_32x32x16_bf16(a0, b0, acc00, 0, 0, 0);
            acc01 = __builtin_amdgcn_mfma_f32_32x32x16_bf16(a0, b1, acc01, 0, 0, 0);
            acc10 = __builtin_amdgcn_mfma_f32_32x32x16_bf16(a1, b0, acc10, 0, 0, 0);
            acc11 = __builtin_amdgcn_mfma_f32_32x32x16_bf16(a1, b1, acc11, 0, 0, 0);
        }
        __builtin_amdgcn_s_setprio(0);
        u16* t;
        t = Ac; Ac = Ap; Ap = t;
        t = Bc; Bc = Bp; Bp = t;
    };

    stage2(Ac, Bc, ca, cb, 0);
    for (int t = 0; t < nterms; ++t) {
        for (int k = 0; k < 15; ++k) step(ca, cb, (k + 1) << 6, true);
        step(na, nb, 0, na != nullptr);
        ca = na; cb = nb; na = fa; nb = fb; fa = nullptr; fb = nullptr;
    }

    // ---- epilogue ----
    __syncthreads();
    u16* Wsm = Adb;      // [c 128][cin 64], slot-swizzled
    u16* Hsm = Bdb;      // [row' 256 = b*128+n][cin 64], slot-swizzled
#pragma unroll
    for (int p = 0; p < 4; ++p) {
        const int row = (p << 5) + srow;
        gld_lds16(Wt + (size_t)row * 64 + sswz,
                  Adb + (p << 11) + ((tid & 192) << 3));
    }

    // Hsm <- bf16(acc); row' = (col>>6)*128 + n
    {
        const f32x16 aa[2][2] = {{acc00, acc01}, {acc10, acc11}};
#pragma unroll
        for (int fm = 0; fm < 2; ++fm)
#pragma unroll
            for (int fn = 0; fn < 2; ++fn)
#pragma unroll
                for (int r = 0; r < 16; ++r) {
                    const int n   = wr + (fm << 5) + (r & 3) + ((r >> 2) << 3) + (lh << 2);
                    const int col = wc + (fn << 5) + l31;
                    const int b   = col >> 6, cin = col & 63;
                    const int rp  = (b << 7) + n;
                    Hsm[(rp << 6) + ((((cin >> 3) ^ (rp & 7))) << 3) + (cin & 7)] =
                        f2bf(aa[fm][fn][r]);
                }
    }
    __syncthreads();

    // second GEMM: 256 rows' x 128 cols, K=64, 32x32 frags; wave w owns 64 rows'
    const float bc0 = bias[l31], bc1 = bias[l31 + 32],
                bc2 = bias[l31 + 64], bc3 = bias[l31 + 96];
    f32x16 q00, q01, q02, q03, q10, q11, q12, q13;
#pragma unroll
    for (int r = 0; r < 16; ++r) {
        q00[r] = bc0; q01[r] = bc1; q02[r] = bc2; q03[r] = bc3;
        q10[r] = bc0; q11[r] = bc1; q12[r] = bc2; q13[r] = bc3;
    }
#pragma unroll
    for (int ks = 0; ks < 4; ++ks) {
        const int off = (((ks << 1) | lh) ^ l7) << 3;
        const short8 ah0 = *(const short8*)&Hsm[(((w << 6) + l31) << 6) + off];
        const short8 ah1 = *(const short8*)&Hsm[(((w << 6) + 32 + l31) << 6) + off];
        const short8 bw0 = *(const short8*)&Wsm[((l31) << 6) + off];
        const short8 bw1 = *(const short8*)&Wsm[((32 + l31) << 6) + off];
        const short8 bw2 = *(const short8*)&Wsm[((64 + l31) << 6) + off];
        const short8 bw3 = *(const short8*)&Wsm[((96 + l31) << 6) + off];
        q00 = __builtin_amdgcn_mfma_f32_32x32x16_bf16(ah0, bw0, q00, 0, 0, 0);
        q01 = __builtin_amdgcn_mfma_f32_32x32x16_bf16(ah0, bw1, q01, 0, 0, 0);
        q02 = __builtin_amdgcn_mfma_f32_32x32x16_bf16(ah0, bw2, q02, 0, 0, 0);
        q03 = __builtin_amdgcn_mfma_f32_32x32x16_bf16(ah0, bw3, q03, 0, 0, 0);
        q10 = __builtin_amdgcn_mfma_f32_32x32x16_bf16(ah1, bw0, q10, 0, 0, 0);
        q11 = __builtin_amdgcn_mfma_f32_32x32x16_bf16(ah1, bw1, q11, 0, 0, 0);
        q12 = __builtin_amdgcn_mfma_f32_32x32x16_bf16(ah1, bw2, q12, 0, 0, 0);
        q13 = __builtin_amdgcn_mfma_f32_32x32x16_bf16(ah1, bw3, q13, 0, 0, 0);
    }

    const int n0g = (i << 10) + row0;
    const int b0i = nt << 1;
    const f32x16 qa[2][4] = {{q00, q01, q02, q03}, {q10, q11, q12, q13}};
#pragma unroll
    for (int fm2 = 0; fm2 < 2; ++fm2)
#pragma unroll
        for (int fn2 = 0; fn2 < 2; ++fn2)
#pragma unroll
            for (int r = 0; r < 16; ++r) {
                const int rowp = (w << 6) + (fm2 << 5) + (r & 3) + ((r >> 2) << 3) + (lh << 2);
                const int b = rowp >> 7, nl = rowp & 127;
                const float lhs = qa[fm2][fn2][r];
                const float rhs = qa[fm2][fn2 + 2][r];
                const float sg  = 1.0f / (1.0f + __expf(-rhs));
                out[((size_t)(n0g + nl) * 32 + b0i + b) * 64 + (fn2 << 5) + l31] = lhs * sg;
            }
}

// ---------------------------------------------------------------------------
extern "C" void kernel_launch(void* const* d_in, const int* in_sizes, int n_in,
                              void* d_out, int out_size, void* d_ws, size_t ws_size,
                              hipStream_t stream)
{
    const float* x    = (const float*)d_in[0];   // (3072, 32, 64)
    const float* adj  = (const float*)d_in[1];   // (1024, 1024)
    const float* wct  = (const float*)d_in[2];   // (2, 1024, 1024)
    const float* W    = (const float*)d_in[3];   // (64, 128)
    const float* bias = (const float*)d_in[4];   // (128,)
    float* out = (float*)d_out;

    char* ws = (char*)d_ws;
    u16* Xt  = (u16*)ws;                    // bf16 [2048][3072]
    u16* Ab  = (u16*)(ws + 12582912);       // 3 x 1M bf16 (Ab|W0b|W1b)
    u16* W0b = Ab + 1048576;
    u16* W1b = Ab + 2097152;
    u16* W0T = (u16*)(ws + 18874368);       // 2 x 1M bf16
    u16* W1T = W0T + 1048576;
    u16* Wt  = (u16*)(ws + 23068672);       // bf16 [128][64]

    prep_kernel<<<5122, 256, 0, stream>>>(x, adj, wct, W, Ab, W0T, W1T, Xt, Wt);
    gemm_h_kernel<<<384, 256, 0, stream>>>(Ab, W0b, W1b, W0T, W1T, Xt, Wt, bias, out);
}

// Round 10
// 56.037 us; speedup vs baseline: 2.1231x; 1.2656x over previous
//
#include <hip/hip_runtime.h>

typedef unsigned short u16;
typedef unsigned int   u32;
typedef __attribute__((ext_vector_type(8))) short short8;
typedef __attribute__((ext_vector_type(4))) float f32x4;

__device__ __forceinline__ u16 f2bf(float f) {
    u32 u = __float_as_uint(f);
    u = (u + 0x7fffu + ((u >> 16) & 1u)) >> 16;
    return (u16)u;
}

__device__ __forceinline__ void gld_lds16(const void* g, void* l) {
    __builtin_amdgcn_global_load_lds(
        (const __attribute__((address_space(1))) u32*)g,
        (__attribute__((address_space(3))) u32*)l, 16, 0, 0);
}

// ---------------------------------------------------------------------------
// prep: 3074 blocks.
//   [0,1024)     adj flat cast -> Ab
//   [1024,1536)  wct tiles: ONE read -> straight cast (W0b/W1b) + transpose
//                (W0T/W1T)
//   [1536,3072)  x transpose+cast -> Xt
//   [3072,3074)  W transpose+cast -> Wt
// ---------------------------------------------------------------------------
__global__ __launch_bounds__(256) void prep_kernel(
    const float* __restrict__ x, const float* __restrict__ adj,
    const float* __restrict__ wct, const float* __restrict__ W,
    u16* __restrict__ Ab, u16* __restrict__ W0T, u16* __restrict__ W1T,
    u16* __restrict__ Xt, u16* __restrict__ Wt)
{
    __shared__ float tile[64][65];
    const int t = threadIdx.x;
    const int bid = blockIdx.x;

    if (bid < 1024) {
        const int i4 = bid * 256 + t;           // 0..262143 float4s of adj
        const float4 v = ((const float4*)adj)[i4];
        ushort4 o;
        o.x = f2bf(v.x); o.y = f2bf(v.y); o.z = f2bf(v.z); o.w = f2bf(v.w);
        ((ushort4*)Ab)[i4] = o;
        return;
    }

    const float* src; int C, R, r0, c0;
    u16* dstT; u16* dstC = nullptr;
    if (bid < 1536) {
        const int q = bid - 1024;
        const int mm = q >> 8, qq = q & 255;
        src  = wct + (size_t)mm * 1048576;
        dstT = mm ? W1T : W0T;
        dstC = Ab + (size_t)(mm + 1) * 1048576;   // W0b / W1b
        C = 1024; R = 1024; r0 = (qq & 15) << 6; c0 = (qq >> 4) << 6;
    } else if (bid < 3072) {
        const int q = bid - 1536;
        src = x; dstT = Xt; C = 2048; R = 3072;
        r0 = (q % 48) << 6; c0 = (q / 48) << 6;
    } else {
        const int q = bid - 3072;
        src = W; dstT = Wt; C = 128; R = 64;
        r0 = 0; c0 = q << 6;
    }

#pragma unroll
    for (int it = 0; it < 4; ++it) {
        const int f4 = it * 256 + t;
        const int r  = f4 >> 4;
        const int c4 = (f4 & 15) << 2;
        const float4 v = *(const float4*)&src[(size_t)(r0 + r) * C + c0 + c4];
        tile[r][c4]     = v.x; tile[r][c4 + 1] = v.y;
        tile[r][c4 + 2] = v.z; tile[r][c4 + 3] = v.w;
        if (dstC) {   // straight cast from registers (wct path), coalesced
            ushort4 o;
            o.x = f2bf(v.x); o.y = f2bf(v.y); o.z = f2bf(v.z); o.w = f2bf(v.w);
            *(ushort4*)&dstC[(size_t)(r0 + r) * 1024 + c0 + c4] = o;
        }
    }
    __syncthreads();
#pragma unroll
    for (int it = 0; it < 4; ++it) {
        const int f4 = it * 256 + t;
        const int u  = f4 >> 4;
        const int v4 = (f4 & 15) << 2;
        ushort4 o;
        o.x = f2bf(tile[v4][u]);     o.y = f2bf(tile[v4 + 1][u]);
        o.z = f2bf(tile[v4 + 2][u]); o.w = f2bf(tile[v4 + 3][u]);
        *(ushort4*)&dstT[(size_t)(c0 + u) * R + r0 + v4] = o;
    }
}

// ---------------------------------------------------------------------------
// gemm+glu fused, SINGLE-BARRIER 2-phase (catalog T3 minimum recipe):
//   per K-step: STAGE(next)->buf^1; ds_read(cur)+MFMA; vmcnt(0); ONE barrier.
//   Stage latency hides under the compute phase; one barrier-drain per step
//   instead of two. Geometry = R5 (proven): 64Mx128N, BK=64, 4 waves 2Mx2N,
//   slot-XOR swizzle (0 conflicts), 768 blocks = 3/CU, balanced i-rounds.
// ---------------------------------------------------------------------------
__global__ __launch_bounds__(256, 3) void gemm_h_kernel(
    const u16* __restrict__ Ab,  const u16* __restrict__ W0b,
    const u16* __restrict__ W1b, const u16* __restrict__ W0T,
    const u16* __restrict__ W1T, const u16* __restrict__ Xt,
    const u16* __restrict__ Wt,  const float* __restrict__ bias,
    float* __restrict__ out)
{
    __shared__ u16 Adb[8192];     // 2 x 4096 elem (16 KB); epilogue: Wsm
    __shared__ u16 Bdb[16384];    // 2 x 8192 elem (32 KB); epilogue: Hsm
    __shared__ float Bias_sm[128];

    const int tid = threadIdx.x;
    const int bid = blockIdx.x;
    const int xcd = bid & 7;
    const int idx = bid >> 3;            // 0..95 within XCD
    const int i   = idx >> 5;            // dispatch round -> block-row 0..2
    const int idp = idx & 31;
    const int row0 = (idp & 15) << 6;
    const int nt   = xcd * 2 + (idp >> 4);
    const int col0 = nt << 7;

    const int l    = tid & 63;
    const int w    = tid >> 6;
    const int wr   = ((tid >> 7) & 1) << 5;  // wave M offset 0/32
    const int wc   = ((tid >> 6) & 1) << 6;  // wave N offset 0/64
    const int lrow = l & 15;
    const int g16  = l >> 4;
    const int rsw  = lrow & 7;

    const int sub  = tid >> 3;                       // 0..31
    const int srck = ((tid & 7) ^ (sub & 7)) << 3;   // pre-swizzled src k
    const int wofs = w << 9;                         // wave-uniform LDS base

    if (tid < 128) Bias_sm[tid] = bias[tid];

    u16 *Ac = Adb, *Ap = Adb + 4096, *Bc = Bdb, *Bp = Bdb + 8192;
    f32x4 acc[2][4] = {};

    auto stageA = [&](u16* dst, const u16* ta, int kel) {
        const u16* ga = ta + (size_t)sub * 1024 + kel + srck;
        gld_lds16(ga,             dst + wofs);
        gld_lds16(ga + 32 * 1024, dst + wofs + 2048);
    };
    auto stageB = [&](u16* dst, const u16* tb, int kel) {
        const u16* gb = tb + (size_t)sub * 3072 + kel + srck;
        gld_lds16(gb,             dst + wofs);
        gld_lds16(gb + 32 * 3072, dst + wofs + 2048);
        gld_lds16(gb + 64 * 3072, dst + wofs + 4096);
        gld_lds16(gb + 96 * 3072, dst + wofs + 6144);
    };
    // SINGLE-BARRIER step: stage first, compute, then {vmcnt(0); barrier}.
    auto step = [&](const u16* pfa, const u16* pfb, int kel, int do_pf) {
        if (do_pf) { stageA(Ap, pfa, kel); stageB(Bp, pfb, kel); }

        short8 af[2][2], bfr[2][4];
#pragma unroll
        for (int kk = 0; kk < 2; ++kk) {
            const int so = (((kk << 2) | g16) ^ rsw) << 3;
#pragma unroll
            for (int fm = 0; fm < 2; ++fm)
                af[kk][fm] = *(const short8*)&Ac[(wr + fm * 16 + lrow) * 64 + so];
#pragma unroll
            for (int fn = 0; fn < 4; ++fn)
                bfr[kk][fn] = *(const short8*)&Bc[(wc + fn * 16 + lrow) * 64 + so];
        }
#pragma unroll
        for (int kk = 0; kk < 2; ++kk)
#pragma unroll
            for (int fm = 0; fm < 2; ++fm)
#pragma unroll
                for (int fn = 0; fn < 4; ++fn)
                    acc[fm][fn] = __builtin_amdgcn_mfma_f32_16x16x32_bf16(
                        af[kk][fm], bfr[kk][fn], acc[fm][fn], 0, 0, 0);

        asm volatile("s_waitcnt vmcnt(0)" ::: "memory");  // my stage landed
        __builtin_amdgcn_s_barrier();                     // everyone's landed
        u16* t;
        t = Ac; Ac = Ap; Ap = t;
        t = Bc; Bc = Bp; Bp = t;
    };
    auto run16 = [&](const u16* ta, const u16* tb,
                     const u16* na, const u16* nb, int hn) {
        for (int k = 1; k < 16; ++k) step(ta, tb, k << 6, 1);
        step(na, nb, 0, hn);
    };

    const size_t xbase = (size_t)col0 * 3072;
    const u16 *a0, *b0, *a1, *b1, *a2 = 0, *b2 = 0;
    int three = 0;
    if (i == 0) {
        a0 = Ab  + row0 * 1024; b0 = Xt + xbase;
        a1 = W0b + row0 * 1024; b1 = Xt + xbase + 1024;
    } else if (i == 1) {
        a0 = W0T + row0 * 1024; b0 = Xt + xbase;
        a1 = Ab  + row0 * 1024; b1 = Xt + xbase + 1024;
        a2 = W1b + row0 * 1024; b2 = Xt + xbase + 2048;
        three = 1;
    } else {
        a0 = W1T + row0 * 1024; b0 = Xt + xbase + 1024;
        a1 = Ab  + row0 * 1024; b1 = Xt + xbase + 2048;
    }

    // prologue: fill buf0, drain, one barrier
    stageA(Ac, a0, 0); stageB(Bc, b0, 0);
    asm volatile("s_waitcnt vmcnt(0)" ::: "memory");
    __builtin_amdgcn_s_barrier();

    run16(a0, b0, a1, b1, 1);
    if (three) { run16(a1, b1, a2, b2, 1); run16(a2, b2, 0, 0, 0); }
    else       { run16(a1, b1, 0, 0, 0); }

    // ---- epilogue: Wsm <- Wt (into A dbuf), Hsm <- bf16(acc) (into B dbuf)
    u16* Wsm = Adb;
    u16* Hsm = Bdb;
#pragma unroll
    for (int p = 0; p < 4; ++p)
        gld_lds16(Wt + (size_t)(p * 32 + sub) * 64 + srck,
                  Adb + p * 2048 + wofs);
#pragma unroll
    for (int fm = 0; fm < 2; ++fm)
#pragma unroll
        for (int fn = 0; fn < 4; ++fn)
#pragma unroll
            for (int r = 0; r < 4; ++r) {
                const int n   = wr + fm * 16 + (g16 << 2) + r;
                const int col = wc + fn * 16 + lrow;
                const int sl2 = ((col >> 3) ^ (n & 7));
                Hsm[n * 128 + (sl2 << 3) + (col & 7)] = f2bf(acc[fm][fn][r]);
            }
    __syncthreads();

    // second GEMM: rows' = b*64+n (128), K = cin 64, N = 128 (lhs|rhs)
    f32x4 acc2[2][8];
#pragma unroll
    for (int fm2 = 0; fm2 < 2; ++fm2)
#pragma unroll
        for (int fn = 0; fn < 8; ++fn) {
            const float bv = Bias_sm[fn * 16 + lrow];
            acc2[fm2][fn] = (f32x4){bv, bv, bv, bv};
        }
#pragma unroll
    for (int kk = 0; kk < 2; ++kk) {
        const int gg = (kk << 2) | g16;
        short8 ah[2], bw[8];
#pragma unroll
        for (int fm2 = 0; fm2 < 2; ++fm2) {
            const int rowp = (w << 5) + (fm2 << 4) + lrow;
            const int b = rowp >> 6, n = rowp & 63;
            const int sl2 = ((b << 3) | gg) ^ (n & 7);
            ah[fm2] = *(const short8*)&Hsm[n * 128 + (sl2 << 3)];
        }
#pragma unroll
        for (int fn = 0; fn < 8; ++fn) {
            const int c = (fn << 4) + lrow;
            const int sl2 = gg ^ (c & 7);
            bw[fn] = *(const short8*)&Wsm[c * 64 + (sl2 << 3)];
        }
#pragma unroll
        for (int fm2 = 0; fm2 < 2; ++fm2)
#pragma unroll
            for (int fn = 0; fn < 8; ++fn)
                acc2[fm2][fn] = __builtin_amdgcn_mfma_f32_16x16x32_bf16(
                    ah[fm2], bw[fn], acc2[fm2][fn], 0, 0, 0);
    }

    const int n0g = i * 1024 + row0;
    const int b0i = nt << 1;
#pragma unroll
    for (int fm2 = 0; fm2 < 2; ++fm2)
#pragma unroll
        for (int fn = 0; fn < 4; ++fn)
#pragma unroll
            for (int r = 0; r < 4; ++r) {
                const int rowp = (w << 5) + (fm2 << 4) + (g16 << 2) + r;
                const int b = rowp >> 6, nl = rowp & 63;
                const float lhs = acc2[fm2][fn][r];
                const float rhs = acc2[fm2][fn + 4][r];
                const float sg  = 1.0f / (1.0f + __expf(-rhs));
                const int c = (fn << 4) + lrow;
                out[((size_t)(n0g + nl) * 32 + (b0i + b)) * 64 + c] = lhs * sg;
            }
}

// ---------------------------------------------------------------------------
extern "C" void kernel_launch(void* const* d_in, const int* in_sizes, int n_in,
                              void* d_out, int out_size, void* d_ws, size_t ws_size,
                              hipStream_t stream)
{
    const float* x    = (const float*)d_in[0];   // (3072, 32, 64)
    const float* adj  = (const float*)d_in[1];   // (1024, 1024)
    const float* wct  = (const float*)d_in[2];   // (2, 1024, 1024)
    const float* W    = (const float*)d_in[3];   // (64, 128)
    const float* bias = (const float*)d_in[4];   // (128,)
    float* out = (float*)d_out;

    char* ws = (char*)d_ws;
    u16* Xt  = (u16*)ws;                    // bf16 [2048][3072]
    u16* Ab  = (u16*)(ws + 12582912);       // 3 x 1M bf16 (Ab|W0b|W1b)
    u16* W0b = Ab + 1048576;
    u16* W1b = Ab + 2097152;
    u16* W0T = (u16*)(ws + 18874368);       // 2 x 1M bf16
    u16* W1T = W0T + 1048576;
    u16* Wt  = (u16*)(ws + 23068672);       // bf16 [128][64]

    prep_kernel<<<3074, 256, 0, stream>>>(x, adj, wct, W, Ab, W0T, W1T, Xt, Wt);
    gemm_h_kernel<<<768, 256, 0, stream>>>(Ab, W0b, W1b, W0T, W1T, Xt, Wt, bias, out);
}